// Round 7
// baseline (216.424 us; speedup 1.0000x reference)
//
#include <hip/hip_runtime.h>

// Problem constants: B=32, C=768, H=W=24 -> HW=576
#define B_  32
#define C_  768
#define HW_ 576

#define NCQ 18               // HW_/32 k-chunks (qk)
#define NCP 24               // C_/32 k-chunks (pv)

typedef _Float16 half8 __attribute__((ext_vector_type(8)));
typedef _Float16 half4 __attribute__((ext_vector_type(4)));
typedef float    f32x4 __attribute__((ext_vector_type(4)));

__device__ __forceinline__ void g2l16(const void* g, void* l) {
    __builtin_amdgcn_global_load_lds(
        (const __attribute__((address_space(1))) unsigned int*)g,
        (__attribute__((address_space(3))) unsigned int*)l, 16, 0, 0);
}

// bijective XCD-aware block swizzle (m204)
__device__ __forceinline__ int xcd_swz(int orig, int nwg) {
    int q = nwg >> 3, rr = nwg & 7;
    int xcd = orig & 7, idx = orig >> 3;
    int base = (xcd < rr) ? xcd * (q + 1) : rr * (q + 1) + (xcd - rr) * q;
    return base + idx;
}

// ---------------------------------------------------------------------------
// prep_all: feat1/feat2 fp32 -> q16/kv16 (row-major fp16 staged tiles) and
// vt (transposed fp16 tiles, via coalesced LDS transpose).
// q16/kv16: [bz][ti128(6)][k0(18)][row(128)][x(4)][8 halves], swizzle
//   chunk x holds k-elems (x ^ ((row>>1)&3))*8..+7.
// vt: [bz][tj192(3)][k0(24)][n(192)][x(4)][8], elem (n,kk)=f2[b][k][n],
//   chunk x holds k-chunk x ^ ((n>>1)&3).
// ---------------------------------------------------------------------------
__global__ __launch_bounds__(256) void prep_all(const float* __restrict__ f1,
                                                const float* __restrict__ f2,
                                                char* __restrict__ q16,
                                                char* __restrict__ kv16,
                                                char* __restrict__ vt,
                                                int b0, int nqk) {
    __shared__ float Vsh[32 * 201];
    const int bid = blockIdx.x;
    if (bid < nqk) {
        int idx = bid * 256 + threadIdx.x;
        int x   = idx & 3;
        int row = (idx >> 2) & 127;
        int t3  = idx >> 9;
        int k0  = t3 % 18;
        int t4  = t3 / 18;
        int ti  = t4 % 6;
        int bz  = t4 / 6;
        int kc  = x ^ ((row >> 1) & 3);
        size_t src = ((size_t)(b0 + bz) * C_ + ti * 128 + row) * HW_ + k0 * 32 + kc * 8;
        f32x4 a0 = *(const f32x4*)(f1 + src);
        f32x4 a1 = *(const f32x4*)(f1 + src + 4);
        f32x4 c0 = *(const f32x4*)(f2 + src);
        f32x4 c1 = *(const f32x4*)(f2 + src + 4);
        half8 ha, hb;
        #pragma unroll
        for (int e = 0; e < 4; ++e) {
            ha[e] = (_Float16)a0[e]; ha[4 + e] = (_Float16)a1[e];
            hb[e] = (_Float16)c0[e]; hb[4 + e] = (_Float16)c1[e];
        }
        *(half8*)(q16  + (size_t)idx * 16) = ha;
        *(half8*)(kv16 + (size_t)idx * 16) = hb;
    } else {
        // vt blocks: one per (bz, k0, tj); coalesced load 32x192 fp32 -> LDS,
        // write transposed fp16 (coalesced 16B stores).
        int bid2 = bid - nqk;
        int bz = bid2 / 72, rem = bid2 % 72, k0 = rem / 3, tj = rem % 3;
        int b  = b0 + bz;
        int t  = threadIdx.x;
        #pragma unroll
        for (int p = 0; p < 6; ++p) {
            int fidx = p * 256 + t;
            int dd = fidx / 48, c4 = fidx % 48;
            f32x4 v = *(const f32x4*)(f2 + ((size_t)b * C_ + k0 * 32 + dd) * HW_ + tj * 192 + c4 * 4);
            #pragma unroll
            for (int e = 0; e < 4; ++e) Vsh[dd * 201 + c4 * 4 + e] = v[e];
        }
        __syncthreads();
        char* ob = vt + ((size_t)(bz * 3 + tj) * NCP + k0) * 12288;
        #pragma unroll
        for (int p = 0; p < 3; ++p) {
            int o = p * 256 + t;
            int x = o & 3, n = o >> 2;
            int kc = x ^ ((n >> 1) & 3);
            half8 h;
            #pragma unroll
            for (int j = 0; j < 8; ++j) h[j] = (_Float16)Vsh[(kc * 8 + j) * 201 + n];
            *(half8*)(ob + o * 16) = h;
        }
    }
}

// ---------------------------------------------------------------------------
// qk6: attn = q @ kv^T. Tile 192x192, 8 waves (4Mx2N, wave 48x96), BK=32,
// ring-3 LDS (72 KB -> 2 blocks/CU), depth-2 counted-vmcnt fine pipeline.
// ---------------------------------------------------------------------------
__global__ __launch_bounds__(512, 4) void qk6(const char* __restrict__ q16,
                                              const char* __restrict__ kv16,
                                              float* __restrict__ attn,
                                              int nwg) {
    __shared__ __align__(16) char S[3][24576];   // per slot: A 12KB | B 12KB
    const int wg = xcd_swz(blockIdx.x, nwg);
    const int bz = wg >> 4, rr0 = wg & 15, ti = rr0 >> 2, tj = rr0 & 3;
    const int t = threadIdx.x, lane = t & 63, w = t >> 6;
    const int rsub = lane >> 2, cb = (lane & 3) * 16;

    const char *p0, *p1, *p2;
    int o0, o1, o2;
    {
        auto arow = [&](int l) {
            int gr = ti * 192 + 16 * l + rsub;
            return q16 + ((size_t)(bz * 6 + (gr >> 7)) * NCQ) * 8192 + (gr & 127) * 64 + cb;
        };
        auto brow = [&](int l) {
            int gd = tj * 192 + 16 * l + rsub;
            return kv16 + ((size_t)(bz * 6 + (gd >> 7)) * NCQ) * 8192 + (gd & 127) * 64 + cb;
        };
        if (w < 4) {
            p0 = arow(2 * w);     o0 = (2 * w) * 1024;
            p1 = arow(2 * w + 1); o1 = (2 * w + 1) * 1024;
            p2 = brow(8 + w);     o2 = 12288 + (8 + w) * 1024;
        } else {
            int v = w - 4;
            p0 = brow(2 * v);     o0 = 12288 + (2 * v) * 1024;
            p1 = brow(2 * v + 1); o1 = 12288 + (2 * v + 1) * 1024;
            p2 = arow(8 + v);     o2 = (8 + v) * 1024;
        }
    }

    const int wr = (w >> 1) * 48, wc = (w & 1) * 96;
    const int r16 = lane & 15, cg = lane >> 4;
    int offA[3], offB[6];
    #pragma unroll
    for (int m = 0; m < 3; ++m) {
        int ra = wr + m * 16 + r16;
        offA[m] = ra * 64 + ((cg ^ ((ra >> 1) & 3)) << 4);
    }
    #pragma unroll
    for (int n = 0; n < 6; ++n) {
        int rb = wc + n * 16 + r16;
        offB[n] = 12288 + rb * 64 + ((cg ^ ((rb >> 1) & 3)) << 4);
    }

    f32x4 acc[3][6] = {};

#define STG(SLOT) do {                          \
        char* sb_ = &S[SLOT][0];                \
        g2l16(p0, sb_ + o0);                    \
        g2l16(p1, sb_ + o1);                    \
        g2l16(p2, sb_ + o2);                    \
        p0 += 8192; p1 += 8192; p2 += 8192;     \
    } while (0)

    STG(0); STG(1);
    int rd = 0, st = 2;
    for (int c = 0; c < NCQ; ++c) {
        if (c + 2 < NCQ) {
            STG(st); st = (st == 2) ? 0 : st + 1;
            asm volatile("s_waitcnt vmcnt(6)" ::: "memory");
        } else if (c + 2 == NCQ) {
            asm volatile("s_waitcnt vmcnt(3)" ::: "memory");
        } else {
            asm volatile("s_waitcnt vmcnt(0)" ::: "memory");
        }
        __builtin_amdgcn_s_barrier();
        const char* sb = &S[rd][0];
        rd = (rd == 2) ? 0 : rd + 1;
        half8 a0 = *(const half8*)(sb + offA[0]);
        half8 a1 = *(const half8*)(sb + offA[1]);
        half8 a2 = *(const half8*)(sb + offA[2]);
        __builtin_amdgcn_s_setprio(1);
        #pragma unroll
        for (int n = 0; n < 6; ++n) {
            half8 bn = *(const half8*)(sb + offB[n]);
            acc[0][n] = __builtin_amdgcn_mfma_f32_16x16x32_f16(a0, bn, acc[0][n], 0, 0, 0);
            acc[1][n] = __builtin_amdgcn_mfma_f32_16x16x32_f16(a1, bn, acc[1][n], 0, 0, 0);
            acc[2][n] = __builtin_amdgcn_mfma_f32_16x16x32_f16(a2, bn, acc[2][n], 0, 0, 0);
        }
        __builtin_amdgcn_s_setprio(0);
        __builtin_amdgcn_s_barrier();
    }
#undef STG

    float* ab = attn + ((size_t)bz * C_ + ti * 192) * C_ + tj * 192;
    const int col = lane & 15, rbase = (lane >> 4) * 4;
    #pragma unroll
    for (int m = 0; m < 3; ++m)
        #pragma unroll
        for (int n = 0; n < 6; ++n)
            #pragma unroll
            for (int rg = 0; rg < 4; ++rg)
                ab[(size_t)(wr + m * 16 + rbase + rg) * C_ + wc + n * 16 + col] = acc[m][n][rg];
}

// ---------------------------------------------------------------------------
// softmax_p16: row softmax of attn (fp32) -> P fp16 staged layout, gamma folded.
// ---------------------------------------------------------------------------
__global__ __launch_bounds__(256) void softmax_p16(const float* __restrict__ attn,
                                                   char* __restrict__ p16,
                                                   const float* __restrict__ gamma) {
    const int R    = blockIdx.x * 4 + (threadIdx.x >> 6);
    const int lane = threadIdx.x & 63;
    const int bz   = R / C_;
    const int c    = R - bz * C_;
    const float* p = attn + (size_t)R * C_;

    f32x4 v[3];
    float mx = -1e30f;
    #pragma unroll
    for (int u = 0; u < 3; ++u) {
        v[u] = *(const f32x4*)(p + (size_t)(lane + 64 * u) * 4);
        #pragma unroll
        for (int e = 0; e < 4; ++e) mx = fmaxf(mx, v[u][e]);
    }
    #pragma unroll
    for (int o = 32; o > 0; o >>= 1) mx = fmaxf(mx, __shfl_xor(mx, o));

    float s = 0.f;
    #pragma unroll
    for (int u = 0; u < 3; ++u)
        #pragma unroll
        for (int e = 0; e < 4; ++e) {
            v[u][e] = __expf(v[u][e] - mx);
            s += v[u][e];
        }
    #pragma unroll
    for (int o = 32; o > 0; o >>= 1) s += __shfl_xor(s, o);
    const float scale = gamma[0] / s;

    const int sw = (c >> 1) & 3;
    char* tb = p16 + ((size_t)(bz * 6 + (c >> 7)) * NCP) * 8192;
    #pragma unroll
    for (int u = 0; u < 3; ++u) {
        int d0 = 4 * lane + 256 * u;
        int k0 = d0 >> 5;
        int x  = ((d0 >> 3) & 3) ^ sw;
        char* addr = tb + (size_t)k0 * 8192 + (c & 127) * 64 + x * 16 + (d0 & 7) * 2;
        half4 hv;
        #pragma unroll
        for (int e = 0; e < 4; ++e) hv[e] = (_Float16)(v[u][e] * scale);
        *(half4*)addr = hv;
    }
}

// ---------------------------------------------------------------------------
// pv7: out = (gamma*P)@V + feat1. Tile 128x192, 4 waves (1Mx4N, wave 128x48),
// BK=32, ring-2 (40 KB LDS -> 4 blocks/CU capacity), counted-vmcnt pipeline.
// 576 blocks -> ALL co-resident (2-3 blocks/CU): no quantization tail,
// inter-block TLP hides staging latency.
// ---------------------------------------------------------------------------
__global__ __launch_bounds__(256, 8) void pv7(const char* __restrict__ p16,
                                              const char* __restrict__ vt,
                                              const float* __restrict__ f1,
                                              float* __restrict__ out,
                                              int b0, int nwg) {
    __shared__ __align__(16) char S[2][20480];   // per slot: A 8KB | B 12KB
    const int wg = xcd_swz(blockIdx.x, nwg);
    const int bz = wg / 18, rem = wg % 18, ti = rem / 3, tj = rem % 3;
    const int t = threadIdx.x, lane = t & 63, w = t >> 6;
    const int rsub = lane >> 2, cb = (lane & 3) * 16;

    const char* Ab = p16 + ((size_t)(bz * 6 + ti) * NCP) * 8192  + rsub * 64 + cb;
    const char* Bb = vt  + ((size_t)(bz * 3 + tj) * NCP) * 12288 + rsub * 64 + cb;

    // 20 loads/chunk, 5 per wave. Loads 0-7: A (16 rows each); 8-19: B.
    const char *p0, *p1, *p2, *p3, *p4;
    int o0, o1, o2, o3, o4;
    long s0, s1, s2, s3, s4;
    if (w == 0) {
        p0 = Ab;          o0 = 0;          s0 = 8192;
        p1 = Ab + 1024;   o1 = 1024;       s1 = 8192;
        p2 = Ab + 2048;   o2 = 2048;       s2 = 8192;
        p3 = Ab + 3072;   o3 = 3072;       s3 = 8192;
        p4 = Ab + 4096;   o4 = 4096;       s4 = 8192;
    } else if (w == 1) {
        p0 = Ab + 5120;   o0 = 5120;       s0 = 8192;
        p1 = Ab + 6144;   o1 = 6144;       s1 = 8192;
        p2 = Ab + 7168;   o2 = 7168;       s2 = 8192;
        p3 = Bb;          o3 = 8192;       s3 = 12288;
        p4 = Bb + 1024;   o4 = 9216;       s4 = 12288;
    } else if (w == 2) {
        p0 = Bb + 2048;   o0 = 10240;      s0 = 12288;
        p1 = Bb + 3072;   o1 = 11264;      s1 = 12288;
        p2 = Bb + 4096;   o2 = 12288;      s2 = 12288;
        p3 = Bb + 5120;   o3 = 13312;      s3 = 12288;
        p4 = Bb + 6144;   o4 = 14336;      s4 = 12288;
    } else {
        p0 = Bb + 7168;   o0 = 15360;      s0 = 12288;
        p1 = Bb + 8192;   o1 = 16384;      s1 = 12288;
        p2 = Bb + 9216;   o2 = 17408;      s2 = 12288;
        p3 = Bb + 10240;  o3 = 18432;      s3 = 12288;
        p4 = Bb + 11264;  o4 = 19456;      s4 = 12288;
    }

    const int wc = w * 48;
    const int r16 = lane & 15, cg = lane >> 4;
    int offA[8], offB[3];
    #pragma unroll
    for (int m = 0; m < 8; ++m) {
        int ra = m * 16 + r16;
        offA[m] = ra * 64 + ((cg ^ ((ra >> 1) & 3)) << 4);
    }
    #pragma unroll
    for (int n = 0; n < 3; ++n) {
        int rb = wc + n * 16 + r16;
        offB[n] = 8192 + rb * 64 + ((cg ^ ((rb >> 1) & 3)) << 4);
    }

    f32x4 acc[8][3] = {};

#define STG(SLOT) do {                          \
        char* sb_ = &S[SLOT][0];                \
        g2l16(p0, sb_ + o0); p0 += s0;          \
        g2l16(p1, sb_ + o1); p1 += s1;          \
        g2l16(p2, sb_ + o2); p2 += s2;          \
        g2l16(p3, sb_ + o3); p3 += s3;          \
        g2l16(p4, sb_ + o4); p4 += s4;          \
    } while (0)

    STG(0);
    for (int c = 0; c < NCP; ++c) {
        const int cur = c & 1;
        if (c + 1 < NCP) {
            STG(cur ^ 1);
            asm volatile("s_waitcnt vmcnt(5)" ::: "memory");
        } else {
            asm volatile("s_waitcnt vmcnt(0)" ::: "memory");
        }
        __builtin_amdgcn_s_barrier();
        const char* sb = &S[cur][0];
        half8 a[8], bb8[3];
        #pragma unroll
        for (int m = 0; m < 8; ++m) a[m]  = *(const half8*)(sb + offA[m]);
        #pragma unroll
        for (int n = 0; n < 3; ++n) bb8[n] = *(const half8*)(sb + offB[n]);
        __builtin_amdgcn_s_setprio(1);
        #pragma unroll
        for (int m = 0; m < 8; ++m)
            #pragma unroll
            for (int n = 0; n < 3; ++n)
                acc[m][n] = __builtin_amdgcn_mfma_f32_16x16x32_f16(a[m], bb8[n], acc[m][n], 0, 0, 0);
        __builtin_amdgcn_s_setprio(0);
        __builtin_amdgcn_s_barrier();
    }
#undef STG

    const int b = b0 + bz;
    const float* f1b = f1 + ((size_t)b * C_ + ti * 128) * HW_ + tj * 192;
    float*       ob  = out + ((size_t)b * C_ + ti * 128) * HW_ + tj * 192;
    const int col = lane & 15, rbase = (lane >> 4) * 4;
    #pragma unroll
    for (int m = 0; m < 8; ++m)
        #pragma unroll
        for (int n = 0; n < 3; ++n)
            #pragma unroll
            for (int rg = 0; rg < 4; ++rg) {
                int r2 = m * 16 + rbase + rg;
                int c2 = wc + n * 16 + col;
                ob[(size_t)r2 * HW_ + c2] = acc[m][n][rg] + f1b[(size_t)r2 * HW_ + c2];
            }
}

// ---------------------------------------------------------------------------
extern "C" void kernel_launch(void* const* d_in, const int* in_sizes, int n_in,
                              void* d_out, int out_size, void* d_ws, size_t ws_size,
                              hipStream_t stream) {
    const float* feat1 = (const float*)d_in[0];
    const float* feat2 = (const float*)d_in[1];
    const float* gamma = (const float*)d_in[2];
    float* out = (float*)d_out;

    const size_t SZ_Q    = (size_t)C_ * HW_ * 2;
    const size_t SZ_ATTN = (size_t)C_ * C_  * 4;
    const size_t SZ_P    = (size_t)C_ * C_  * 2;
    const size_t per_batch = SZ_ATTN + 3 * SZ_Q + SZ_P;

    int nb = (int)(ws_size / per_batch);
    if (nb < 1) nb = 1;
    if (nb > B_) nb = B_;

    char* ws    = (char*)d_ws;
    float* attn = (float*)ws;
    char* q16   = ws + (size_t)nb * SZ_ATTN;
    char* kv16  = q16 + (size_t)nb * SZ_Q;
    char* vtb   = kv16 + (size_t)nb * SZ_Q;
    char* p16   = vtb + (size_t)nb * SZ_Q;

    for (int b0 = 0; b0 < B_; b0 += nb) {
        int cur = (B_ - b0 < nb) ? (B_ - b0) : nb;
        prep_all<<<cur * 288, 256, 0, stream>>>(feat1, feat2, q16, kv16, vtb, b0, cur * 216);
        qk6<<<cur * 16, 512, 0, stream>>>(q16, kv16, attn, cur * 16);
        softmax_p16<<<cur * 192, 256, 0, stream>>>(attn, p16, gamma);
        pv7<<<cur * 18, 256, 0, stream>>>(p16, vtb, feat1, out, b0, cur * 18);
    }
}

// Round 8
// 146.670 us; speedup vs baseline: 1.4756x; 1.4756x over previous
//
#include <hip/hip_runtime.h>

// Problem constants: B=32, C=768, H=W=24 -> HW=576
#define B_  32
#define C_  768
#define HW_ 576

#define NCQ 18               // HW_/32 k-chunks (qk)
#define NCP 24               // C_/32 k-chunks (pv)

typedef _Float16 half8 __attribute__((ext_vector_type(8)));
typedef _Float16 half4 __attribute__((ext_vector_type(4)));
typedef float    f32x4 __attribute__((ext_vector_type(4)));

__device__ __forceinline__ void g2l16(const void* g, void* l) {
    __builtin_amdgcn_global_load_lds(
        (const __attribute__((address_space(1))) unsigned int*)g,
        (__attribute__((address_space(3))) unsigned int*)l, 16, 0, 0);
}

// bijective XCD-aware block swizzle (m204)
__device__ __forceinline__ int xcd_swz(int orig, int nwg) {
    int q = nwg >> 3, rr = nwg & 7;
    int xcd = orig & 7, idx = orig >> 3;
    int base = (xcd < rr) ? xcd * (q + 1) : rr * (q + 1) + (xcd - rr) * q;
    return base + idx;
}

#define VM(N) asm volatile("s_waitcnt vmcnt(" #N ")" ::: "memory")

// ---------------------------------------------------------------------------
// prep_all: feat1/feat2 fp32 -> q16/kv16 (row-major fp16 staged tiles) and
// vt (transposed fp16 tiles via coalesced LDS transpose).
// ---------------------------------------------------------------------------
__global__ __launch_bounds__(256) void prep_all(const float* __restrict__ f1,
                                                const float* __restrict__ f2,
                                                char* __restrict__ q16,
                                                char* __restrict__ kv16,
                                                char* __restrict__ vt,
                                                int b0, int nqk) {
    __shared__ float Vsh[32 * 201];
    const int bid = blockIdx.x;
    if (bid < nqk) {
        int idx = bid * 256 + threadIdx.x;
        int x   = idx & 3;
        int row = (idx >> 2) & 127;
        int t3  = idx >> 9;
        int k0  = t3 % 18;
        int t4  = t3 / 18;
        int ti  = t4 % 6;
        int bz  = t4 / 6;
        int kc  = x ^ ((row >> 1) & 3);
        size_t src = ((size_t)(b0 + bz) * C_ + ti * 128 + row) * HW_ + k0 * 32 + kc * 8;
        f32x4 a0 = *(const f32x4*)(f1 + src);
        f32x4 a1 = *(const f32x4*)(f1 + src + 4);
        f32x4 c0 = *(const f32x4*)(f2 + src);
        f32x4 c1 = *(const f32x4*)(f2 + src + 4);
        half8 ha, hb;
        #pragma unroll
        for (int e = 0; e < 4; ++e) {
            ha[e] = (_Float16)a0[e]; ha[4 + e] = (_Float16)a1[e];
            hb[e] = (_Float16)c0[e]; hb[4 + e] = (_Float16)c1[e];
        }
        *(half8*)(q16  + (size_t)idx * 16) = ha;
        *(half8*)(kv16 + (size_t)idx * 16) = hb;
    } else {
        int bid2 = bid - nqk;
        int bz = bid2 / 72, rem = bid2 % 72, k0 = rem / 3, tj = rem % 3;
        int b  = b0 + bz;
        int t  = threadIdx.x;
        #pragma unroll
        for (int p = 0; p < 6; ++p) {
            int fidx = p * 256 + t;
            int dd = fidx / 48, c4 = fidx % 48;
            f32x4 v = *(const f32x4*)(f2 + ((size_t)b * C_ + k0 * 32 + dd) * HW_ + tj * 192 + c4 * 4);
            #pragma unroll
            for (int e = 0; e < 4; ++e) Vsh[dd * 201 + c4 * 4 + e] = v[e];
        }
        __syncthreads();
        char* ob = vt + ((size_t)(bz * 3 + tj) * NCP + k0) * 12288;
        #pragma unroll
        for (int p = 0; p < 3; ++p) {
            int o = p * 256 + t;
            int x = o & 3, n = o >> 2;
            int kc = x ^ ((n >> 1) & 3);
            half8 h;
            #pragma unroll
            for (int j = 0; j < 8; ++j) h[j] = (_Float16)Vsh[(kc * 8 + j) * 201 + n];
            *(half8*)(ob + o * 16) = h;
        }
    }
}

// ---------------------------------------------------------------------------
// qk6: attn = q @ kv^T. Tile 192x192, 8 waves (4Mx2N), BK=32, ring-3,
// depth-2 counted-vmcnt fine pipeline. (unchanged from round 6)
// ---------------------------------------------------------------------------
__global__ __launch_bounds__(512, 4) void qk6(const char* __restrict__ q16,
                                              const char* __restrict__ kv16,
                                              float* __restrict__ attn,
                                              int nwg) {
    __shared__ __align__(16) char S[3][24576];
    const int wg = xcd_swz(blockIdx.x, nwg);
    const int bz = wg >> 4, rr0 = wg & 15, ti = rr0 >> 2, tj = rr0 & 3;
    const int t = threadIdx.x, lane = t & 63, w = t >> 6;
    const int rsub = lane >> 2, cb = (lane & 3) * 16;

    const char *p0, *p1, *p2;
    int o0, o1, o2;
    {
        auto arow = [&](int l) {
            int gr = ti * 192 + 16 * l + rsub;
            return q16 + ((size_t)(bz * 6 + (gr >> 7)) * NCQ) * 8192 + (gr & 127) * 64 + cb;
        };
        auto brow = [&](int l) {
            int gd = tj * 192 + 16 * l + rsub;
            return kv16 + ((size_t)(bz * 6 + (gd >> 7)) * NCQ) * 8192 + (gd & 127) * 64 + cb;
        };
        if (w < 4) {
            p0 = arow(2 * w);     o0 = (2 * w) * 1024;
            p1 = arow(2 * w + 1); o1 = (2 * w + 1) * 1024;
            p2 = brow(8 + w);     o2 = 12288 + (8 + w) * 1024;
        } else {
            int v = w - 4;
            p0 = brow(2 * v);     o0 = 12288 + (2 * v) * 1024;
            p1 = brow(2 * v + 1); o1 = 12288 + (2 * v + 1) * 1024;
            p2 = arow(8 + v);     o2 = (8 + v) * 1024;
        }
    }

    const int wr = (w >> 1) * 48, wc = (w & 1) * 96;
    const int r16 = lane & 15, cg = lane >> 4;
    int offA[3], offB[6];
    #pragma unroll
    for (int m = 0; m < 3; ++m) {
        int ra = wr + m * 16 + r16;
        offA[m] = ra * 64 + ((cg ^ ((ra >> 1) & 3)) << 4);
    }
    #pragma unroll
    for (int n = 0; n < 6; ++n) {
        int rb = wc + n * 16 + r16;
        offB[n] = 12288 + rb * 64 + ((cg ^ ((rb >> 1) & 3)) << 4);
    }

    f32x4 acc[3][6] = {};

#define STG(SLOT) do {                          \
        char* sb_ = &S[SLOT][0];                \
        g2l16(p0, sb_ + o0);                    \
        g2l16(p1, sb_ + o1);                    \
        g2l16(p2, sb_ + o2);                    \
        p0 += 8192; p1 += 8192; p2 += 8192;     \
    } while (0)

    STG(0); STG(1);
    int rd = 0, st = 2;
    for (int c = 0; c < NCQ; ++c) {
        if (c + 2 < NCQ) {
            STG(st); st = (st == 2) ? 0 : st + 1;
            VM(6);
        } else if (c + 2 == NCQ) {
            VM(3);
        } else {
            VM(0);
        }
        __builtin_amdgcn_s_barrier();
        const char* sb = &S[rd][0];
        rd = (rd == 2) ? 0 : rd + 1;
        half8 a0 = *(const half8*)(sb + offA[0]);
        half8 a1 = *(const half8*)(sb + offA[1]);
        half8 a2 = *(const half8*)(sb + offA[2]);
        __builtin_amdgcn_s_setprio(1);
        #pragma unroll
        for (int n = 0; n < 6; ++n) {
            half8 bn = *(const half8*)(sb + offB[n]);
            acc[0][n] = __builtin_amdgcn_mfma_f32_16x16x32_f16(a0, bn, acc[0][n], 0, 0, 0);
            acc[1][n] = __builtin_amdgcn_mfma_f32_16x16x32_f16(a1, bn, acc[1][n], 0, 0, 0);
            acc[2][n] = __builtin_amdgcn_mfma_f32_16x16x32_f16(a2, bn, acc[2][n], 0, 0, 0);
        }
        __builtin_amdgcn_s_setprio(0);
        __builtin_amdgcn_s_barrier();
    }
#undef STG

    float* ab = attn + ((size_t)bz * C_ + ti * 192) * C_ + tj * 192;
    const int col = lane & 15, rbase = (lane >> 4) * 4;
    #pragma unroll
    for (int m = 0; m < 3; ++m)
        #pragma unroll
        for (int n = 0; n < 6; ++n)
            #pragma unroll
            for (int rg = 0; rg < 4; ++rg)
                ab[(size_t)(wr + m * 16 + rbase + rg) * C_ + wc + n * 16 + col] = acc[m][n][rg];
}

// ---------------------------------------------------------------------------
// sm_stats: per-row softmax stats of attn (fp32). Writes stats[R] = {m, gamma/s}.
// Reduction code identical to previous softmax (bitwise-same m, s).
// ---------------------------------------------------------------------------
__global__ __launch_bounds__(256) void sm_stats(const float* __restrict__ attn,
                                                float* __restrict__ stats,
                                                const float* __restrict__ gamma) {
    const int R    = blockIdx.x * 4 + (threadIdx.x >> 6);
    const int lane = threadIdx.x & 63;
    const float* p = attn + (size_t)R * C_;

    f32x4 v[3];
    float mx = -1e30f;
    #pragma unroll
    for (int u = 0; u < 3; ++u) {
        v[u] = *(const f32x4*)(p + (size_t)(lane + 64 * u) * 4);
        #pragma unroll
        for (int e = 0; e < 4; ++e) mx = fmaxf(mx, v[u][e]);
    }
    #pragma unroll
    for (int o = 32; o > 0; o >>= 1) mx = fmaxf(mx, __shfl_xor(mx, o));

    float s = 0.f;
    #pragma unroll
    for (int u = 0; u < 3; ++u)
        #pragma unroll
        for (int e = 0; e < 4; ++e) {
            s += __expf(v[u][e] - mx);
        }
    #pragma unroll
    for (int o = 32; o > 0; o >>= 1) s += __shfl_xor(s, o);

    if (lane == 0) {
        ((float2*)stats)[R] = make_float2(mx, gamma[0] / s);
    }
}

// ---------------------------------------------------------------------------
// pv8: out = (gamma*P)@V + feat1 with softmax FUSED into A-staging.
// Tile 128x192, 8 waves (2Mx4N, wave 64x48), BK=32, ring-3 (60KB -> 2/CU).
// A: reg-stage attn fp32 chunk -> exp(x-m)*scale -> fp16 ds_write (swizzled).
// B: vt via g2l, per-wave counted vmcnt.
// ---------------------------------------------------------------------------
__global__ __launch_bounds__(512, 4) void pv8(const float* __restrict__ attn,
                                              const char* __restrict__ vt,
                                              const float* __restrict__ stats,
                                              const float* __restrict__ f1,
                                              float* __restrict__ out,
                                              int b0, int nwg) {
    __shared__ __align__(16) char S[3][20480];   // per slot: A 8KB | B 12KB
    const int wg = xcd_swz(blockIdx.x, nwg);
    const int bz = wg / 18, rem = wg % 18, ti = rem / 3, tj = rem % 3;
    const int t = threadIdx.x, lane = t & 63, w = t >> 6;
    const int rsub = lane >> 2, cbb = (lane & 3) * 16;

    // ---- A staging: each thread owns 2 rows x one f32x4 d-group ----
    const int r0 = t >> 3;            // rows 0..63
    const int r1 = 64 + r0;           // rows 64..127
    const int d4 = t & 7;
    const float* srcA0 = attn + ((size_t)bz * C_ + ti * 128 + r0) * C_ + d4 * 4;
    const float* srcA1 = attn + ((size_t)bz * C_ + ti * 128 + r1) * C_ + d4 * 4;
    const float2 ms0 = ((const float2*)stats)[bz * C_ + ti * 128 + r0];
    const float2 ms1 = ((const float2*)stats)[bz * C_ + ti * 128 + r1];
    const int aw0 = r0 * 64 + (((d4 >> 1) ^ ((r0 >> 1) & 3)) << 4) + (d4 & 1) * 8;
    const int aw1 = r1 * 64 + (((d4 >> 1) ^ ((r1 >> 1) & 3)) << 4) + (d4 & 1) * 8;

    // ---- B staging (g2l): w<4 -> rows {32w, 32w+16} (2 loads); w>=4 -> row 128+16(w-4) ----
    const char* vbase = vt + ((size_t)(bz * 3 + tj) * NCP) * 12288;
    const char *pB0, *pB1;
    int ob0, ob1;
    if (w < 4) {
        pB0 = vbase + (32 * w + rsub) * 64 + cbb;          ob0 = 8192 + (32 * w) * 64;
        pB1 = vbase + (32 * w + 16 + rsub) * 64 + cbb;     ob1 = 8192 + (32 * w + 16) * 64;
    } else {
        pB0 = vbase + (128 + 16 * (w - 4) + rsub) * 64 + cbb;
        ob0 = 8192 + (128 + 16 * (w - 4)) * 64;
        pB1 = vbase; ob1 = 0;  // unused
    }

    const int wr = (w >> 2) * 64, wc = (w & 3) * 48;
    const int r16 = lane & 15, cg = lane >> 4;
    int offA[4], offB[3];
    #pragma unroll
    for (int m = 0; m < 4; ++m) {
        int ra = wr + m * 16 + r16;
        offA[m] = ra * 64 + ((cg ^ ((ra >> 1) & 3)) << 4);
    }
    #pragma unroll
    for (int n = 0; n < 3; ++n) {
        int rb = wc + n * 16 + r16;
        offB[n] = 8192 + rb * 64 + ((cg ^ ((rb >> 1) & 3)) << 4);
    }

    f32x4 acc[4][3] = {};
    f32x4 va0, va1;

#define STG_B(SLOT) do {                                  \
        g2l16(pB0, &S[SLOT][0] + ob0); pB0 += 12288;      \
        if (w < 4) { g2l16(pB1, &S[SLOT][0] + ob1); pB1 += 12288; } \
    } while (0)
#define LD_A() do { va0 = *(const f32x4*)srcA0; va1 = *(const f32x4*)srcA1; \
                    srcA0 += 32; srcA1 += 32; } while (0)
#define WR_A(SLOT) do {                                                \
        half4 h0, h1;                                                  \
        _Pragma("unroll")                                              \
        for (int e = 0; e < 4; ++e) {                                  \
            h0[e] = (_Float16)(__expf(va0[e] - ms0.x) * ms0.y);        \
            h1[e] = (_Float16)(__expf(va1[e] - ms1.x) * ms1.y);        \
        }                                                              \
        *(half4*)(&S[SLOT][0] + aw0) = h0;                             \
        *(half4*)(&S[SLOT][0] + aw1) = h1;                             \
    } while (0)

    // prologue: A(0) -> LDS slot0; B(0)->slot0, B(1)->slot1; A(1) loads in flight
    LD_A();
    WR_A(0);
    STG_B(0); STG_B(1);
    LD_A();

    for (int c = 0; c < NCP; ++c) {
        const int cur = c % 3;
        asm volatile("s_waitcnt lgkmcnt(0)" ::: "memory");  // A ds_writes drained
        __builtin_amdgcn_s_barrier();
        if (c + 2 < NCP) STG_B((c + 2) % 3);
        // wait all B(c) landed: queue = [B(c+1)k, A(c+1):2, B(c+2)k]
        if (c < NCP - 2)      { if (w < 4) VM(6); else VM(4); }
        else if (c == NCP - 2){ if (w < 4) VM(4); else VM(3); }
        else                  { VM(0); }
        __builtin_amdgcn_s_barrier();

        const char* sb = &S[cur][0];
        half8 a[4], bb8[3];
        #pragma unroll
        for (int m = 0; m < 4; ++m) a[m]  = *(const half8*)(sb + offA[m]);
        #pragma unroll
        for (int n = 0; n < 3; ++n) bb8[n] = *(const half8*)(sb + offB[n]);
        __builtin_amdgcn_s_setprio(1);
        #pragma unroll
        for (int m = 0; m < 4; ++m)
            #pragma unroll
            for (int n = 0; n < 3; ++n)
                acc[m][n] = __builtin_amdgcn_mfma_f32_16x16x32_f16(a[m], bb8[n], acc[m][n], 0, 0, 0);
        __builtin_amdgcn_s_setprio(0);

        if (c + 1 < NCP) {
            WR_A((c + 1) % 3);            // compiler waits va regs (vmcnt) itself
            if (c + 2 < NCP) LD_A();      // A(c+2) in flight across next iter
        }
    }
#undef STG_B
#undef LD_A
#undef WR_A

    const int b = b0 + bz;
    const float* f1b = f1 + ((size_t)b * C_ + ti * 128) * HW_ + tj * 192;
    float*       ob  = out + ((size_t)b * C_ + ti * 128) * HW_ + tj * 192;
    const int col = lane & 15, rbase = (lane >> 4) * 4;
    #pragma unroll
    for (int m = 0; m < 4; ++m)
        #pragma unroll
        for (int n = 0; n < 3; ++n)
            #pragma unroll
            for (int rg = 0; rg < 4; ++rg) {
                int r2 = wr + m * 16 + rbase + rg;
                int c2 = wc + n * 16 + col;
                ob[(size_t)r2 * HW_ + c2] = acc[m][n][rg] + f1b[(size_t)r2 * HW_ + c2];
            }
}

// ---------------------------------------------------------------------------
extern "C" void kernel_launch(void* const* d_in, const int* in_sizes, int n_in,
                              void* d_out, int out_size, void* d_ws, size_t ws_size,
                              hipStream_t stream) {
    const float* feat1 = (const float*)d_in[0];
    const float* feat2 = (const float*)d_in[1];
    const float* gamma = (const float*)d_in[2];
    float* out = (float*)d_out;

    const size_t SZ_Q    = (size_t)C_ * HW_ * 2;      //   884,736 B/batch
    const size_t SZ_ATTN = (size_t)C_ * C_  * 4;      // 2,359,296 B/batch
    const size_t SZ_ST   = (size_t)C_ * 8;            //     6,144 B/batch
    const size_t per_batch = SZ_ATTN + 3 * SZ_Q + SZ_ST;

    int nb = (int)(ws_size / per_batch);
    if (nb < 1) nb = 1;
    if (nb > B_) nb = B_;

    char* ws    = (char*)d_ws;
    float* attn = (float*)ws;
    char* q16   = ws + (size_t)nb * SZ_ATTN;
    char* kv16  = q16 + (size_t)nb * SZ_Q;
    char* vtb   = kv16 + (size_t)nb * SZ_Q;
    float* stats = (float*)(vtb + (size_t)nb * SZ_Q);

    for (int b0 = 0; b0 < B_; b0 += nb) {
        int cur = (B_ - b0 < nb) ? (B_ - b0) : nb;
        prep_all<<<cur * 288, 256, 0, stream>>>(feat1, feat2, q16, kv16, vtb, b0, cur * 216);
        qk6<<<cur * 16, 512, 0, stream>>>(q16, kv16, attn, cur * 16);
        sm_stats<<<cur * 192, 256, 0, stream>>>(attn, stats, gamma);
        pv8<<<cur * 18, 512, 0, stream>>>(attn, vtb, stats, feat1, out, b0, cur * 18);
    }
}

// Round 10
// 143.142 us; speedup vs baseline: 1.5120x; 1.0247x over previous
//
#include <hip/hip_runtime.h>

// Problem constants: B=32, C=768, H=W=24 -> HW=576
#define B_  32
#define C_  768
#define HW_ 576

#define NCQ 18               // HW_/32 k-chunks (qk)
#define NCP 24               // C_/32 k-chunks (pv)

typedef _Float16 half8 __attribute__((ext_vector_type(8)));
typedef _Float16 half4 __attribute__((ext_vector_type(4)));
typedef float    f32x4 __attribute__((ext_vector_type(4)));

__device__ __forceinline__ void g2l16(const void* g, void* l) {
    __builtin_amdgcn_global_load_lds(
        (const __attribute__((address_space(1))) unsigned int*)g,
        (__attribute__((address_space(3))) unsigned int*)l, 16, 0, 0);
}

#define VM(N) asm volatile("s_waitcnt vmcnt(" #N ")" ::: "memory")

// XCD alignment: every kernel makes bz the fastest grid coordinate, so
// blockIdx % 8 == bz % 8 -> all blocks of a batch land on one XCD and
// producer->consumer traffic stays in that XCD's L2.

// ---------------------------------------------------------------------------
// prep_all: feat1/feat2 fp32 -> q16/kv16 (row-major fp16 staged tiles) and
// vt (transposed fp16 tiles via coalesced LDS transpose).
// ---------------------------------------------------------------------------
__global__ __launch_bounds__(256) void prep_all(const float* __restrict__ f1,
                                                const float* __restrict__ f2,
                                                char* __restrict__ q16,
                                                char* __restrict__ kv16,
                                                char* __restrict__ vt,
                                                int b0, int cur, int nqk) {
    __shared__ float Vsh[32 * 201];
    const int bid = blockIdx.x;
    if (bid < nqk) {
        const int bz = bid % cur, u = bid / cur;        // u in [0,216)
        int g   = u * 256 + threadIdx.x;                // [ti][k0][row][x]
        int x   = g & 3;
        int row = (g >> 2) & 127;
        int t3  = g >> 9;                               // ti*18 + k0
        int k0  = t3 % 18;
        int ti  = t3 / 18;
        int kc  = x ^ ((row >> 1) & 3);
        size_t src = ((size_t)(b0 + bz) * C_ + ti * 128 + row) * HW_ + k0 * 32 + kc * 8;
        f32x4 a0 = *(const f32x4*)(f1 + src);
        f32x4 a1 = *(const f32x4*)(f1 + src + 4);
        f32x4 c0 = *(const f32x4*)(f2 + src);
        f32x4 c1 = *(const f32x4*)(f2 + src + 4);
        half8 ha, hb;
        #pragma unroll
        for (int e = 0; e < 4; ++e) {
            ha[e] = (_Float16)a0[e]; ha[4 + e] = (_Float16)a1[e];
            hb[e] = (_Float16)c0[e]; hb[4 + e] = (_Float16)c1[e];
        }
        size_t dst = ((size_t)(((size_t)bz * 6 + ti) * 18 + k0) << 9) | (g & 511);
        *(half8*)(q16  + dst * 16) = ha;
        *(half8*)(kv16 + dst * 16) = hb;
    } else {
        int bid2 = bid - nqk;
        const int bz = bid2 % cur, u = bid2 / cur;      // u in [0,72)
        int k0 = u / 3, tj = u % 3;
        int b  = b0 + bz;
        int t  = threadIdx.x;
        #pragma unroll
        for (int p = 0; p < 6; ++p) {
            int fidx = p * 256 + t;
            int dd = fidx / 48, c4 = fidx % 48;
            f32x4 v = *(const f32x4*)(f2 + ((size_t)b * C_ + k0 * 32 + dd) * HW_ + tj * 192 + c4 * 4);
            #pragma unroll
            for (int e = 0; e < 4; ++e) Vsh[dd * 201 + c4 * 4 + e] = v[e];
        }
        __syncthreads();
        char* ob = vt + ((size_t)(bz * 3 + tj) * NCP + k0) * 12288;
        #pragma unroll
        for (int p = 0; p < 3; ++p) {
            int o = p * 256 + t;
            int x = o & 3, n = o >> 2;
            int kc = x ^ ((n >> 1) & 3);
            half8 h;
            #pragma unroll
            for (int j = 0; j < 8; ++j) h[j] = (_Float16)Vsh[(kc * 8 + j) * 201 + n];
            *(half8*)(ob + o * 16) = h;
        }
    }
}

// ---------------------------------------------------------------------------
// qk6: attn = q @ kv^T. Tile 192x192, 8 waves (4Mx2N), BK=32, ring-3,
// depth-2 counted-vmcnt fine pipeline. Epilogue: per-tile softmax partials
// {rowmax, rowsumexp} -> part[bz][row][tj*2 + col-half] (8 slots/row:
// each row is covered by TWO waves (wc halves) -> each writes its own slot).
// ---------------------------------------------------------------------------
__global__ __launch_bounds__(512, 4) void qk6(const char* __restrict__ q16,
                                              const char* __restrict__ kv16,
                                              float* __restrict__ attn,
                                              float2* __restrict__ part,
                                              int cur) {
    __shared__ __align__(16) char S[3][24576];
    const int wg = blockIdx.x;
    const int bz = wg % cur, u = wg / cur;   // u in [0,16)
    const int ti = u >> 2, tj = u & 3;
    const int t = threadIdx.x, lane = t & 63, w = t >> 6;
    const int rsub = lane >> 2, cb = (lane & 3) * 16;

    const char *p0, *p1, *p2;
    int o0, o1, o2;
    {
        auto arow = [&](int l) {
            int gr = ti * 192 + 16 * l + rsub;
            return q16 + ((size_t)(bz * 6 + (gr >> 7)) * NCQ) * 8192 + (gr & 127) * 64 + cb;
        };
        auto brow = [&](int l) {
            int gd = tj * 192 + 16 * l + rsub;
            return kv16 + ((size_t)(bz * 6 + (gd >> 7)) * NCQ) * 8192 + (gd & 127) * 64 + cb;
        };
        if (w < 4) {
            p0 = arow(2 * w);     o0 = (2 * w) * 1024;
            p1 = arow(2 * w + 1); o1 = (2 * w + 1) * 1024;
            p2 = brow(8 + w);     o2 = 12288 + (8 + w) * 1024;
        } else {
            int v = w - 4;
            p0 = brow(2 * v);     o0 = 12288 + (2 * v) * 1024;
            p1 = brow(2 * v + 1); o1 = 12288 + (2 * v + 1) * 1024;
            p2 = arow(8 + v);     o2 = (8 + v) * 1024;
        }
    }

    const int wr = (w >> 1) * 48, wc = (w & 1) * 96;
    const int r16 = lane & 15, cg = lane >> 4;
    int offA[3], offB[6];
    #pragma unroll
    for (int m = 0; m < 3; ++m) {
        int ra = wr + m * 16 + r16;
        offA[m] = ra * 64 + ((cg ^ ((ra >> 1) & 3)) << 4);
    }
    #pragma unroll
    for (int n = 0; n < 6; ++n) {
        int rb = wc + n * 16 + r16;
        offB[n] = 12288 + rb * 64 + ((cg ^ ((rb >> 1) & 3)) << 4);
    }

    f32x4 acc[3][6] = {};

#define STG(SLOT) do {                          \
        char* sb_ = &S[SLOT][0];                \
        g2l16(p0, sb_ + o0);                    \
        g2l16(p1, sb_ + o1);                    \
        g2l16(p2, sb_ + o2);                    \
        p0 += 8192; p1 += 8192; p2 += 8192;     \
    } while (0)

    STG(0); STG(1);
    int rd = 0, st = 2;
    for (int c = 0; c < NCQ; ++c) {
        if (c + 2 < NCQ) {
            STG(st); st = (st == 2) ? 0 : st + 1;
            VM(6);
        } else if (c + 2 == NCQ) {
            VM(3);
        } else {
            VM(0);
        }
        __builtin_amdgcn_s_barrier();
        const char* sb = &S[rd][0];
        rd = (rd == 2) ? 0 : rd + 1;
        half8 a0 = *(const half8*)(sb + offA[0]);
        half8 a1 = *(const half8*)(sb + offA[1]);
        half8 a2 = *(const half8*)(sb + offA[2]);
        __builtin_amdgcn_s_setprio(1);
        #pragma unroll
        for (int n = 0; n < 6; ++n) {
            half8 bn = *(const half8*)(sb + offB[n]);
            acc[0][n] = __builtin_amdgcn_mfma_f32_16x16x32_f16(a0, bn, acc[0][n], 0, 0, 0);
            acc[1][n] = __builtin_amdgcn_mfma_f32_16x16x32_f16(a1, bn, acc[1][n], 0, 0, 0);
            acc[2][n] = __builtin_amdgcn_mfma_f32_16x16x32_f16(a2, bn, acc[2][n], 0, 0, 0);
        }
        __builtin_amdgcn_s_setprio(0);
        __builtin_amdgcn_s_barrier();
    }
#undef STG

    float* ab = attn + ((size_t)bz * C_ + ti * 192) * C_ + tj * 192;
    const int col = lane & 15, rbase = (lane >> 4) * 4;
    #pragma unroll
    for (int m = 0; m < 3; ++m)
        #pragma unroll
        for (int n = 0; n < 6; ++n)
            #pragma unroll
            for (int rg = 0; rg < 4; ++rg)
                ab[(size_t)(wr + m * 16 + rbase + rg) * C_ + wc + n * 16 + col] = acc[m][n][rg];

    // per-(row, 96-col half) softmax partials; slot = tj*2 + (w&1).
    const int half = w & 1;
    #pragma unroll
    for (int m = 0; m < 3; ++m)
        #pragma unroll
        for (int rg = 0; rg < 4; ++rg) {
            float mx = -1e30f;
            #pragma unroll
            for (int n = 0; n < 6; ++n) mx = fmaxf(mx, acc[m][n][rg]);
            #pragma unroll
            for (int o = 1; o < 16; o <<= 1) mx = fmaxf(mx, __shfl_xor(mx, o));
            float s = 0.f;
            #pragma unroll
            for (int n = 0; n < 6; ++n) s += __expf(acc[m][n][rg] - mx);
            #pragma unroll
            for (int o = 1; o < 16; o <<= 1) s += __shfl_xor(s, o);
            if ((lane & 15) == 0) {
                int row = wr + m * 16 + (lane >> 4) * 4 + rg;
                part[((size_t)bz * C_ + ti * 192 + row) * 8 + tj * 2 + half] =
                    make_float2(mx, s);
            }
        }
}

// ---------------------------------------------------------------------------
// sm_combine: stats[R] = {m, gamma/s} from 8 per-(tile,half) partials per row.
// ---------------------------------------------------------------------------
__global__ __launch_bounds__(256) void sm_combine(const float2* __restrict__ part,
                                                  float2* __restrict__ stats,
                                                  const float* __restrict__ gamma,
                                                  int cur) {
    const int bid = blockIdx.x;
    const int bz = bid % cur, u = bid / cur;     // u in [0,3)
    const int R = bz * C_ + u * 256 + threadIdx.x;
    float2 p[8];
    #pragma unroll
    for (int i = 0; i < 8; ++i) p[i] = part[(size_t)R * 8 + i];
    float m = p[0].x;
    #pragma unroll
    for (int i = 1; i < 8; ++i) m = fmaxf(m, p[i].x);
    float s = 0.f;
    #pragma unroll
    for (int i = 0; i < 8; ++i) s += p[i].y * __expf(p[i].x - m);
    stats[R] = make_float2(m, gamma[0] / s);
}

// ---------------------------------------------------------------------------
// pv8: out = (gamma*P)@V + feat1 with softmax fused into A-staging.
// Tile 128x192, 8 waves (2Mx4N), BK=32, ring-3 (60KB -> 2/CU).
// ---------------------------------------------------------------------------
__global__ __launch_bounds__(512, 4) void pv8(const float* __restrict__ attn,
                                              const char* __restrict__ vt,
                                              const float2* __restrict__ stats,
                                              const float* __restrict__ f1,
                                              float* __restrict__ out,
                                              int b0, int cur) {
    __shared__ __align__(16) char S[3][20480];   // per slot: A 8KB | B 12KB
    const int wg = blockIdx.x;
    const int bz = wg % cur, u = wg / cur;       // u in [0,18)
    const int ti = u / 3, tj = u % 3;
    const int t = threadIdx.x, lane = t & 63, w = t >> 6;
    const int rsub = lane >> 2, cbb = (lane & 3) * 16;

    // ---- A staging: each thread owns 2 rows x one f32x4 d-group ----
    const int r0 = t >> 3;            // rows 0..63
    const int r1 = 64 + r0;           // rows 64..127
    const int d4 = t & 7;
    const float* srcA0 = attn + ((size_t)bz * C_ + ti * 128 + r0) * C_ + d4 * 4;
    const float* srcA1 = attn + ((size_t)bz * C_ + ti * 128 + r1) * C_ + d4 * 4;
    const float2 ms0 = stats[bz * C_ + ti * 128 + r0];
    const float2 ms1 = stats[bz * C_ + ti * 128 + r1];
    const int aw0 = r0 * 64 + (((d4 >> 1) ^ ((r0 >> 1) & 3)) << 4) + (d4 & 1) * 8;
    const int aw1 = r1 * 64 + (((d4 >> 1) ^ ((r1 >> 1) & 3)) << 4) + (d4 & 1) * 8;

    // ---- B staging (g2l) ----
    const char* vbase = vt + ((size_t)(bz * 3 + tj) * NCP) * 12288;
    const char *pB0, *pB1;
    int ob0, ob1;
    if (w < 4) {
        pB0 = vbase + (32 * w + rsub) * 64 + cbb;          ob0 = 8192 + (32 * w) * 64;
        pB1 = vbase + (32 * w + 16 + rsub) * 64 + cbb;     ob1 = 8192 + (32 * w + 16) * 64;
    } else {
        pB0 = vbase + (128 + 16 * (w - 4) + rsub) * 64 + cbb;
        ob0 = 8192 + (128 + 16 * (w - 4)) * 64;
        pB1 = vbase; ob1 = 0;  // unused
    }

    const int wr = (w >> 2) * 64, wc = (w & 3) * 48;
    const int r16 = lane & 15, cg = lane >> 4;
    int offA[4], offB[3];
    #pragma unroll
    for (int m = 0; m < 4; ++m) {
        int ra = wr + m * 16 + r16;
        offA[m] = ra * 64 + ((cg ^ ((ra >> 1) & 3)) << 4);
    }
    #pragma unroll
    for (int n = 0; n < 3; ++n) {
        int rb = wc + n * 16 + r16;
        offB[n] = 8192 + rb * 64 + ((cg ^ ((rb >> 1) & 3)) << 4);
    }

    f32x4 acc[4][3] = {};
    f32x4 va0, va1;

#define STG_B(SLOT) do {                                  \
        g2l16(pB0, &S[SLOT][0] + ob0); pB0 += 12288;      \
        if (w < 4) { g2l16(pB1, &S[SLOT][0] + ob1); pB1 += 12288; } \
    } while (0)
#define LD_A() do { va0 = *(const f32x4*)srcA0; va1 = *(const f32x4*)srcA1; \
                    srcA0 += 32; srcA1 += 32; } while (0)
#define WR_A(SLOT) do {                                                \
        half4 h0, h1;                                                  \
        _Pragma("unroll")                                              \
        for (int e = 0; e < 4; ++e) {                                  \
            h0[e] = (_Float16)(__expf(va0[e] - ms0.x) * ms0.y);        \
            h1[e] = (_Float16)(__expf(va1[e] - ms1.x) * ms1.y);        \
        }                                                              \
        *(half4*)(&S[SLOT][0] + aw0) = h0;                             \
        *(half4*)(&S[SLOT][0] + aw1) = h1;                             \
    } while (0)

    LD_A();
    WR_A(0);
    STG_B(0); STG_B(1);
    LD_A();

    for (int c = 0; c < NCP; ++c) {
        const int cur3 = c % 3;
        asm volatile("s_waitcnt lgkmcnt(0)" ::: "memory");
        __builtin_amdgcn_s_barrier();
        if (c + 2 < NCP) STG_B((c + 2) % 3);
        if (c < NCP - 2)      { if (w < 4) VM(6); else VM(4); }
        else if (c == NCP - 2){ if (w < 4) VM(4); else VM(3); }
        else                  { VM(0); }
        __builtin_amdgcn_s_barrier();

        const char* sb = &S[cur3][0];
        half8 a[4], bb8[3];
        #pragma unroll
        for (int m = 0; m < 4; ++m) a[m]  = *(const half8*)(sb + offA[m]);
        #pragma unroll
        for (int n = 0; n < 3; ++n) bb8[n] = *(const half8*)(sb + offB[n]);
        __builtin_amdgcn_s_setprio(1);
        #pragma unroll
        for (int m = 0; m < 4; ++m)
            #pragma unroll
            for (int n = 0; n < 3; ++n)
                acc[m][n] = __builtin_amdgcn_mfma_f32_16x16x32_f16(a[m], bb8[n], acc[m][n], 0, 0, 0);
        __builtin_amdgcn_s_setprio(0);

        if (c + 1 < NCP) {
            WR_A((c + 1) % 3);
            if (c + 2 < NCP) LD_A();
        }
    }
#undef STG_B
#undef LD_A
#undef WR_A

    const int b = b0 + bz;
    const float* f1b = f1 + ((size_t)b * C_ + ti * 128) * HW_ + tj * 192;
    float*       ob  = out + ((size_t)b * C_ + ti * 128) * HW_ + tj * 192;
    const int col = lane & 15, rbase = (lane >> 4) * 4;
    #pragma unroll
    for (int m = 0; m < 4; ++m)
        #pragma unroll
        for (int n = 0; n < 3; ++n)
            #pragma unroll
            for (int rg = 0; rg < 4; ++rg) {
                int r2 = wr + m * 16 + rbase + rg;
                int c2 = wc + n * 16 + col;
                ob[(size_t)r2 * HW_ + c2] = acc[m][n][rg] + f1b[(size_t)r2 * HW_ + c2];
            }
}

// ---------------------------------------------------------------------------
extern "C" void kernel_launch(void* const* d_in, const int* in_sizes, int n_in,
                              void* d_out, int out_size, void* d_ws, size_t ws_size,
                              hipStream_t stream) {
    const float* feat1 = (const float*)d_in[0];
    const float* feat2 = (const float*)d_in[1];
    const float* gamma = (const float*)d_in[2];
    float* out = (float*)d_out;

    const size_t SZ_Q    = (size_t)C_ * HW_ * 2;      //   884,736 B/batch
    const size_t SZ_ATTN = (size_t)C_ * C_  * 4;      // 2,359,296 B/batch
    const size_t SZ_PART = (size_t)C_ * 8 * 8;        //    49,152 B/batch
    const size_t SZ_ST   = (size_t)C_ * 8;            //     6,144 B/batch
    const size_t per_batch = SZ_ATTN + 3 * SZ_Q + SZ_PART + SZ_ST;

    int nb = (int)(ws_size / per_batch);
    if (nb < 1) nb = 1;
    if (nb > B_) nb = B_;

    char* ws     = (char*)d_ws;
    float* attn  = (float*)ws;
    char* q16    = ws + (size_t)nb * SZ_ATTN;
    char* kv16   = q16 + (size_t)nb * SZ_Q;
    char* vtb    = kv16 + (size_t)nb * SZ_Q;
    float2* part = (float2*)(vtb + (size_t)nb * SZ_Q);
    float2* stats = (float2*)((char*)part + (size_t)nb * SZ_PART);

    for (int b0 = 0; b0 < B_; b0 += nb) {
        int cur = (B_ - b0 < nb) ? (B_ - b0) : nb;
        prep_all<<<cur * 288, 256, 0, stream>>>(feat1, feat2, q16, kv16, vtb, b0, cur, cur * 216);
        qk6<<<cur * 16, 512, 0, stream>>>(q16, kv16, attn, part, cur);
        sm_combine<<<cur * 3, 256, 0, stream>>>(part, stats, gamma, cur);
        pv8<<<cur * 18, 512, 0, stream>>>(attn, vtb, stats, feat1, out, b0, cur);
    }
}

// Round 13
// 141.167 us; speedup vs baseline: 1.5331x; 1.0140x over previous
//
#include <hip/hip_runtime.h>

// Problem constants: B=32, C=768, H=W=24 -> HW=576
#define B_  32
#define C_  768
#define HW_ 576

#define NCQ 18               // HW_/32 k-chunks (qk)
#define NCP 24               // C_/32 k-chunks (pv)

typedef _Float16 half8 __attribute__((ext_vector_type(8)));
typedef _Float16 half4 __attribute__((ext_vector_type(4)));
typedef float    f32x4 __attribute__((ext_vector_type(4)));

__device__ __forceinline__ void g2l16(const void* g, void* l) {
    __builtin_amdgcn_global_load_lds(
        (const __attribute__((address_space(1))) unsigned int*)g,
        (__attribute__((address_space(3))) unsigned int*)l, 16, 0, 0);
}

#define VM(N) asm volatile("s_waitcnt vmcnt(" #N ")" ::: "memory")

// ---------------------------------------------------------------------------
// prep_all: feat1/feat2 fp32 -> q16/kv16 (row-major fp16 staged tiles) and
// vt (transposed fp16 tiles via coalesced LDS transpose). (round-10 exact)
// ---------------------------------------------------------------------------
__global__ __launch_bounds__(256) void prep_all(const float* __restrict__ f1,
                                                const float* __restrict__ f2,
                                                char* __restrict__ q16,
                                                char* __restrict__ kv16,
                                                char* __restrict__ vt,
                                                int b0, int cur, int nqk) {
    __shared__ float Vsh[32 * 201];
    const int bid = blockIdx.x;
    if (bid < nqk) {
        const int bz = bid % cur, u = bid / cur;        // u in [0,216)
        int g   = u * 256 + threadIdx.x;                // [ti][k0][row][x]
        int x   = g & 3;
        int row = (g >> 2) & 127;
        int t3  = g >> 9;                               // ti*18 + k0
        int k0  = t3 % 18;
        int ti  = t3 / 18;
        int kc  = x ^ ((row >> 1) & 3);
        size_t src = ((size_t)(b0 + bz) * C_ + ti * 128 + row) * HW_ + k0 * 32 + kc * 8;
        f32x4 a0 = *(const f32x4*)(f1 + src);
        f32x4 a1 = *(const f32x4*)(f1 + src + 4);
        f32x4 c0 = *(const f32x4*)(f2 + src);
        f32x4 c1 = *(const f32x4*)(f2 + src + 4);
        half8 ha, hb;
        #pragma unroll
        for (int e = 0; e < 4; ++e) {
            ha[e] = (_Float16)a0[e]; ha[4 + e] = (_Float16)a1[e];
            hb[e] = (_Float16)c0[e]; hb[4 + e] = (_Float16)c1[e];
        }
        size_t dst = ((size_t)(((size_t)bz * 6 + ti) * 18 + k0) << 9) | (g & 511);
        *(half8*)(q16  + dst * 16) = ha;
        *(half8*)(kv16 + dst * 16) = hb;
    } else {
        int bid2 = bid - nqk;
        const int bz = bid2 % cur, u = bid2 / cur;      // u in [0,72)
        int k0 = u / 3, tj = u % 3;
        int b  = b0 + bz;
        int t  = threadIdx.x;
        #pragma unroll
        for (int p = 0; p < 6; ++p) {
            int fidx = p * 256 + t;
            int dd = fidx / 48, c4 = fidx % 48;
            f32x4 v = *(const f32x4*)(f2 + ((size_t)b * C_ + k0 * 32 + dd) * HW_ + tj * 192 + c4 * 4);
            #pragma unroll
            for (int e = 0; e < 4; ++e) Vsh[dd * 201 + c4 * 4 + e] = v[e];
        }
        __syncthreads();
        char* ob = vt + ((size_t)(bz * 3 + tj) * NCP + k0) * 12288;
        #pragma unroll
        for (int p = 0; p < 3; ++p) {
            int o = p * 256 + t;
            int x = o & 3, n = o >> 2;
            int kc = x ^ ((n >> 1) & 3);
            half8 h;
            #pragma unroll
            for (int j = 0; j < 8; ++j) h[j] = (_Float16)Vsh[(kc * 8 + j) * 201 + n];
            *(half8*)(ob + o * 16) = h;
        }
    }
}

// ---------------------------------------------------------------------------
// qk6: attn(fp32) = q @ kv^T. Tile 192x192, 8 waves (4Mx2N), BK=32, ring-3,
// depth-2 counted-vmcnt pipeline. fp32 attn store + fp32 softmax partials.
// (round-10 exact)
// ---------------------------------------------------------------------------
__global__ __launch_bounds__(512, 4) void qk6(const char* __restrict__ q16,
                                              const char* __restrict__ kv16,
                                              float* __restrict__ attn,
                                              float2* __restrict__ part,
                                              int cur) {
    __shared__ __align__(16) char S[3][24576];
    const int wg = blockIdx.x;
    const int bz = wg % cur, u = wg / cur;   // u in [0,16)
    const int ti = u >> 2, tj = u & 3;
    const int t = threadIdx.x, lane = t & 63, w = t >> 6;
    const int rsub = lane >> 2, cb = (lane & 3) * 16;

    const char *p0, *p1, *p2;
    int o0, o1, o2;
    {
        auto arow = [&](int l) {
            int gr = ti * 192 + 16 * l + rsub;
            return q16 + ((size_t)(bz * 6 + (gr >> 7)) * NCQ) * 8192 + (gr & 127) * 64 + cb;
        };
        auto brow = [&](int l) {
            int gd = tj * 192 + 16 * l + rsub;
            return kv16 + ((size_t)(bz * 6 + (gd >> 7)) * NCQ) * 8192 + (gd & 127) * 64 + cb;
        };
        if (w < 4) {
            p0 = arow(2 * w);     o0 = (2 * w) * 1024;
            p1 = arow(2 * w + 1); o1 = (2 * w + 1) * 1024;
            p2 = brow(8 + w);     o2 = 12288 + (8 + w) * 1024;
        } else {
            int v = w - 4;
            p0 = brow(2 * v);     o0 = 12288 + (2 * v) * 1024;
            p1 = brow(2 * v + 1); o1 = 12288 + (2 * v + 1) * 1024;
            p2 = arow(8 + v);     o2 = (8 + v) * 1024;
        }
    }

    const int wr = (w >> 1) * 48, wc = (w & 1) * 96;
    const int r16 = lane & 15, cg = lane >> 4;
    int offA[3], offB[6];
    #pragma unroll
    for (int m = 0; m < 3; ++m) {
        int ra = wr + m * 16 + r16;
        offA[m] = ra * 64 + ((cg ^ ((ra >> 1) & 3)) << 4);
    }
    #pragma unroll
    for (int n = 0; n < 6; ++n) {
        int rb = wc + n * 16 + r16;
        offB[n] = 12288 + rb * 64 + ((cg ^ ((rb >> 1) & 3)) << 4);
    }

    f32x4 acc[3][6] = {};

#define STG(SLOT) do {                          \
        char* sb_ = &S[SLOT][0];                \
        g2l16(p0, sb_ + o0);                    \
        g2l16(p1, sb_ + o1);                    \
        g2l16(p2, sb_ + o2);                    \
        p0 += 8192; p1 += 8192; p2 += 8192;     \
    } while (0)

    STG(0); STG(1);
    int rd = 0, st = 2;
    for (int c = 0; c < NCQ; ++c) {
        if (c + 2 < NCQ) {
            STG(st); st = (st == 2) ? 0 : st + 1;
            VM(6);
        } else if (c + 2 == NCQ) {
            VM(3);
        } else {
            VM(0);
        }
        __builtin_amdgcn_s_barrier();
        const char* sb = &S[rd][0];
        rd = (rd == 2) ? 0 : rd + 1;
        half8 a0 = *(const half8*)(sb + offA[0]);
        half8 a1 = *(const half8*)(sb + offA[1]);
        half8 a2 = *(const half8*)(sb + offA[2]);
        __builtin_amdgcn_s_setprio(1);
        #pragma unroll
        for (int n = 0; n < 6; ++n) {
            half8 bn = *(const half8*)(sb + offB[n]);
            acc[0][n] = __builtin_amdgcn_mfma_f32_16x16x32_f16(a0, bn, acc[0][n], 0, 0, 0);
            acc[1][n] = __builtin_amdgcn_mfma_f32_16x16x32_f16(a1, bn, acc[1][n], 0, 0, 0);
            acc[2][n] = __builtin_amdgcn_mfma_f32_16x16x32_f16(a2, bn, acc[2][n], 0, 0, 0);
        }
        __builtin_amdgcn_s_setprio(0);
        __builtin_amdgcn_s_barrier();
    }
#undef STG

    float* ab = attn + ((size_t)bz * C_ + ti * 192) * C_ + tj * 192;
    const int col = lane & 15, rbase = (lane >> 4) * 4;
    #pragma unroll
    for (int m = 0; m < 3; ++m)
        #pragma unroll
        for (int n = 0; n < 6; ++n)
            #pragma unroll
            for (int rg = 0; rg < 4; ++rg)
                ab[(size_t)(wr + m * 16 + rbase + rg) * C_ + wc + n * 16 + col] = acc[m][n][rg];

    // per-(row, 96-col half) softmax partials; slot = tj*2 + (w&1).
    const int half = w & 1;
    #pragma unroll
    for (int m = 0; m < 3; ++m)
        #pragma unroll
        for (int rg = 0; rg < 4; ++rg) {
            float mx = -1e30f;
            #pragma unroll
            for (int n = 0; n < 6; ++n) mx = fmaxf(mx, acc[m][n][rg]);
            #pragma unroll
            for (int o = 1; o < 16; o <<= 1) mx = fmaxf(mx, __shfl_xor(mx, o));
            float s = 0.f;
            #pragma unroll
            for (int n = 0; n < 6; ++n) s += __expf(acc[m][n][rg] - mx);
            #pragma unroll
            for (int o = 1; o < 16; o <<= 1) s += __shfl_xor(s, o);
            if ((lane & 15) == 0) {
                int row = wr + m * 16 + (lane >> 4) * 4 + rg;
                part[((size_t)bz * C_ + ti * 192 + row) * 8 + tj * 2 + half] =
                    make_float2(mx, s);
            }
        }
}

// ---------------------------------------------------------------------------
// sm_combine: stats[R] = {m, gamma/s} from 8 per-(tile,half) partials per row.
// ---------------------------------------------------------------------------
__global__ __launch_bounds__(256) void sm_combine(const float2* __restrict__ part,
                                                  float2* __restrict__ stats,
                                                  const float* __restrict__ gamma,
                                                  int cur) {
    const int bid = blockIdx.x;
    const int bz = bid % cur, u = bid / cur;     // u in [0,3)
    const int R = bz * C_ + u * 256 + threadIdx.x;
    float2 p[8];
    #pragma unroll
    for (int i = 0; i < 8; ++i) p[i] = part[(size_t)R * 8 + i];
    float m = p[0].x;
    #pragma unroll
    for (int i = 1; i < 8; ++i) m = fmaxf(m, p[i].x);
    float s = 0.f;
    #pragma unroll
    for (int i = 0; i < 8; ++i) s += p[i].y * __expf(p[i].x - m);
    stats[R] = make_float2(m, gamma[0] / s);
}

// ---------------------------------------------------------------------------
// pv10: out = (gamma*P)@V + feat1, softmax fused into A-staging.
// SINGLE DELTA vs round-10 pv8: paired chunks per phase (12 phases of 2
// chunks instead of 24 of 1). Ring-4 of the SAME 20KB slot layout (80KB ->
// 2 blocks/CU), depth-1 pair prefetch. Same per-wave load assignments, same
// arithmetic order (chunk 2p then 2p+1) -> bit-identical output.
// ---------------------------------------------------------------------------
__global__ __launch_bounds__(512, 4) void pv10(const float* __restrict__ attn,
                                               const char* __restrict__ vt,
                                               const float2* __restrict__ stats,
                                               const float* __restrict__ f1,
                                               float* __restrict__ out,
                                               int b0, int cur) {
    __shared__ __align__(16) char S[4][20480];   // per slot: A 8KB | B 12KB
    const int wg = blockIdx.x;
    const int bz = wg % cur, u = wg / cur;       // u in [0,18)
    const int ti = u / 3, tj = u % 3;
    const int t = threadIdx.x, lane = t & 63, w = t >> 6;
    const int rsub = lane >> 2, cbb = (lane & 3) * 16;

    // ---- A staging: each thread owns 2 rows x one f32x4 d-group per chunk ----
    const int r0 = t >> 3;            // rows 0..63
    const int r1 = 64 + r0;           // rows 64..127
    const int d4 = t & 7;
    const float* srcA0 = attn + ((size_t)bz * C_ + ti * 128 + r0) * C_ + d4 * 4;
    const float* srcA1 = attn + ((size_t)bz * C_ + ti * 128 + r1) * C_ + d4 * 4;
    const float2 ms0 = stats[bz * C_ + ti * 128 + r0];
    const float2 ms1 = stats[bz * C_ + ti * 128 + r1];
    const int aw0 = r0 * 64 + (((d4 >> 1) ^ ((r0 >> 1) & 3)) << 4) + (d4 & 1) * 8;
    const int aw1 = r1 * 64 + (((d4 >> 1) ^ ((r1 >> 1) & 3)) << 4) + (d4 & 1) * 8;

    // ---- B staging (g2l): same per-wave assignment as round 10 ----
    const char* vbase = vt + ((size_t)(bz * 3 + tj) * NCP) * 12288;
    const char *pB0, *pB1;
    int ob0, ob1;
    if (w < 4) {
        pB0 = vbase + (32 * w + rsub) * 64 + cbb;          ob0 = 8192 + (32 * w) * 64;
        pB1 = vbase + (32 * w + 16 + rsub) * 64 + cbb;     ob1 = 8192 + (32 * w + 16) * 64;
    } else {
        pB0 = vbase + (128 + 16 * (w - 4) + rsub) * 64 + cbb;
        ob0 = 8192 + (128 + 16 * (w - 4)) * 64;
        pB1 = vbase; ob1 = 0;  // unused
    }

    const int wr = (w >> 2) * 64, wc = (w & 3) * 48;
    const int r16 = lane & 15, cg = lane >> 4;
    int offA[4], offB[3];
    #pragma unroll
    for (int m = 0; m < 4; ++m) {
        int ra = wr + m * 16 + r16;
        offA[m] = ra * 64 + ((cg ^ ((ra >> 1) & 3)) << 4);
    }
    #pragma unroll
    for (int n = 0; n < 3; ++n) {
        int rb = wc + n * 16 + r16;
        offB[n] = 8192 + rb * 64 + ((cg ^ ((rb >> 1) & 3)) << 4);
    }

    f32x4 acc[4][3] = {};
    f32x4 vaA0, vaA1;    // named set A (even chunk of pair)
    f32x4 vaB0, vaB1;    // named set B (odd  chunk of pair)

#define STG_B(SLOT) do {                                  \
        g2l16(pB0, &S[SLOT][0] + ob0); pB0 += 12288;      \
        if (w < 4) { g2l16(pB1, &S[SLOT][0] + ob1); pB1 += 12288; } \
    } while (0)
#define LD_A(V0, V1) do { V0 = *(const f32x4*)srcA0; V1 = *(const f32x4*)srcA1; \
                          srcA0 += 32; srcA1 += 32; } while (0)
#define WR_A(SLOT, V0, V1) do {                                        \
        half4 h0, h1;                                                  \
        _Pragma("unroll")                                              \
        for (int e = 0; e < 4; ++e) {                                  \
            h0[e] = (_Float16)(__expf(V0[e] - ms0.x) * ms0.y);         \
            h1[e] = (_Float16)(__expf(V1[e] - ms1.x) * ms1.y);         \
        }                                                              \
        *(half4*)(&S[SLOT][0] + aw0) = h0;                             \
        *(half4*)(&S[SLOT][0] + aw1) = h1;                             \
    } while (0)
#define MFMA_SLOT(SB) do {                                             \
        const char* sb_ = (SB);                                        \
        half8 a_[4], b_[3];                                            \
        _Pragma("unroll")                                              \
        for (int m = 0; m < 4; ++m) a_[m] = *(const half8*)(sb_ + offA[m]); \
        _Pragma("unroll")                                              \
        for (int n = 0; n < 3; ++n) b_[n] = *(const half8*)(sb_ + offB[n]); \
        _Pragma("unroll")                                              \
        for (int m = 0; m < 4; ++m)                                    \
            _Pragma("unroll")                                          \
            for (int n = 0; n < 3; ++n)                                \
                acc[m][n] = __builtin_amdgcn_mfma_f32_16x16x32_f16(a_[m], b_[n], acc[m][n], 0, 0, 0); \
    } while (0)

    // prologue: A(0)->slot0, A(1)->slot1; B(0)->slot0, B(1)->slot1;
    // preload A(2)->setA, A(3)->setB.
    LD_A(vaA0, vaA1);
    WR_A(0, vaA0, vaA1);
    LD_A(vaB0, vaB1);
    WR_A(1, vaB0, vaB1);
    STG_B(0); STG_B(1);
    LD_A(vaA0, vaA1);        // chunk 2
    LD_A(vaB0, vaB1);        // chunk 3

    for (int p = 0; p < 12; ++p) {
        const int sa = (2 * p) & 3;          // slot of chunk 2p
        asm volatile("s_waitcnt lgkmcnt(0)" ::: "memory");
        __builtin_amdgcn_s_barrier();
        if (p < 11) { STG_B((sa + 2) & 3); STG_B((sa + 3) & 3); }
        if (p < 11) { if (w < 4) VM(8); else VM(6); }
        else        { VM(0); }
        __builtin_amdgcn_s_barrier();

        __builtin_amdgcn_s_setprio(1);
        MFMA_SLOT(&S[sa][0]);
        MFMA_SLOT(&S[sa ^ 1][0]);            // slot of chunk 2p+1
        __builtin_amdgcn_s_setprio(0);

        if (p < 11) {
            WR_A((sa + 2) & 3, vaA0, vaA1);  // chunk 2p+2
            WR_A((sa + 3) & 3, vaB0, vaB1);  // chunk 2p+3
            if (p < 10) {
                LD_A(vaA0, vaA1);            // chunk 2p+4
                LD_A(vaB0, vaB1);            // chunk 2p+5
            }
        }
    }
#undef MFMA_SLOT
#undef WR_A
#undef LD_A
#undef STG_B

    const int b = b0 + bz;
    const float* f1b = f1 + ((size_t)b * C_ + ti * 128) * HW_ + tj * 192;
    float*       ob  = out + ((size_t)b * C_ + ti * 128) * HW_ + tj * 192;
    const int col = lane & 15, rbase = (lane >> 4) * 4;
    #pragma unroll
    for (int m = 0; m < 4; ++m)
        #pragma unroll
        for (int n = 0; n < 3; ++n)
            #pragma unroll
            for (int rg = 0; rg < 4; ++rg) {
                int r2 = wr + m * 16 + rbase + rg;
                int c2 = wc + n * 16 + col;
                ob[(size_t)r2 * HW_ + c2] = acc[m][n][rg] + f1b[(size_t)r2 * HW_ + c2];
            }
}

// ---------------------------------------------------------------------------
extern "C" void kernel_launch(void* const* d_in, const int* in_sizes, int n_in,
                              void* d_out, int out_size, void* d_ws, size_t ws_size,
                              hipStream_t stream) {
    const float* feat1 = (const float*)d_in[0];
    const float* feat2 = (const float*)d_in[1];
    const float* gamma = (const float*)d_in[2];
    float* out = (float*)d_out;

    const size_t SZ_Q    = (size_t)C_ * HW_ * 2;      //   884,736 B/batch
    const size_t SZ_ATTN = (size_t)C_ * C_  * 4;      // 2,359,296 B/batch (fp32)
    const size_t SZ_PART = (size_t)C_ * 8 * 8;        //    49,152 B/batch
    const size_t SZ_ST   = (size_t)C_ * 8;            //     6,144 B/batch
    const size_t per_batch = SZ_ATTN + 3 * SZ_Q + SZ_PART + SZ_ST;

    int nb = (int)(ws_size / per_batch);
    if (nb < 1) nb = 1;
    if (nb > B_) nb = B_;

    char* ws     = (char*)d_ws;
    float* attn  = (float*)ws;
    char* q16    = ws + (size_t)nb * SZ_ATTN;
    char* kv16   = q16 + (size_t)nb * SZ_Q;
    char* vtb    = kv16 + (size_t)nb * SZ_Q;
    float2* part = (float2*)(vtb + (size_t)nb * SZ_Q);
    float2* stats = (float2*)((char*)part + (size_t)nb * SZ_PART);

    for (int b0 = 0; b0 < B_; b0 += nb) {
        int cur = (B_ - b0 < nb) ? (B_ - b0) : nb;
        prep_all<<<cur * 288, 256, 0, stream>>>(feat1, feat2, q16, kv16, vtb, b0, cur, cur * 216);
        qk6<<<cur * 16, 512, 0, stream>>>(q16, kv16, attn, part, cur);
        sm_combine<<<cur * 3, 256, 0, stream>>>(part, stats, gamma, cur);
        pv10<<<cur * 18, 512, 0, stream>>>(attn, vtb, stats, feat1, out, b0, cur);
    }
}